// Round 1
// baseline (2069.761 us; speedup 1.0000x reference)
//
#include <hip/hip_runtime.h>

constexpr int D = 64;

// ---------------- deg / dinv ----------------
__global__ __launch_bounds__(256) void k_count_deg(const int* __restrict__ ei,
                                                   int* __restrict__ deg, int E) {
    int e = blockIdx.x * blockDim.x + threadIdx.x;
    if (e < E) atomicAdd(&deg[ei[E + e]], 1);   // dst row of edge_index
}

__global__ __launch_bounds__(256) void k_dinv(const int* __restrict__ deg,
                                              float* __restrict__ dinv, int N) {
    int n = blockIdx.x * blockDim.x + threadIdx.x;
    if (n < N) dinv[n] = rsqrtf((float)(deg[n] + 1));  // +1 self-loop
}

// ---------------- init x = concat(u, it); acc = x ----------------
__global__ __launch_bounds__(256) void k_init_x(const float4* __restrict__ u,
                                                const float4* __restrict__ it,
                                                float4* __restrict__ x,
                                                float4* __restrict__ acc,
                                                int UD4, int total4) {
    int i = blockIdx.x * blockDim.x + threadIdx.x;
    int stride = gridDim.x * blockDim.x;
    for (; i < total4; i += stride) {
        float4 v = (i < UD4) ? u[i] : it[i - UD4];
        x[i] = v;
        acc[i] = v;
    }
}

// ---------------- h = x @ W ; out = h*dinv^2 + b (self-loop + bias fused) ----
__global__ __launch_bounds__(256) void k_gemm(const float* __restrict__ x,
                                              const float* __restrict__ W,
                                              const float* __restrict__ b,
                                              const float* __restrict__ dinv,
                                              float* __restrict__ h,
                                              float* __restrict__ out, int N) {
    __shared__ float Wl[D * D];
    for (int i = threadIdx.x; i < D * D; i += blockDim.x) Wl[i] = W[i];
    __syncthreads();

    const int lane = threadIdx.x & 63;
    const int wave = threadIdx.x >> 6;
    const int wavesTotal = gridDim.x * (blockDim.x >> 6);
    int row = blockIdx.x * (blockDim.x >> 6) + wave;
    const float bl = b[lane];

    for (; row < N; row += wavesTotal) {
        float xv = x[row * D + lane];
        float acc = 0.f;
#pragma unroll
        for (int k = 0; k < D; ++k) {
            float xk = __shfl(xv, k);
            acc = fmaf(xk, Wl[k * D + lane], acc);
        }
        h[row * D + lane] = acc;
        float di = dinv[row];
        out[row * D + lane] = fmaf(acc, di * di, bl);
    }
}

// ---------------- edge scatter: out[dst] += h[src] * dinv[src]*dinv[dst] ----
__global__ __launch_bounds__(256) void k_scatter(const int* __restrict__ ei,
                                                 const float* __restrict__ h,
                                                 const float* __restrict__ dinv,
                                                 float* __restrict__ out, int E) {
    int gw = (int)((blockIdx.x * (size_t)blockDim.x + threadIdx.x) >> 6);
    int lane = threadIdx.x & 63;
    if (gw >= E) return;
    int src = ei[gw];
    int dst = ei[E + gw];
    float nrm = dinv[src] * dinv[dst];
    float v = h[src * D + lane] * nrm;
    atomicAdd(&out[dst * D + lane], v);
}

// ---------------- acc = (acc + out) * scale ----------------
__global__ __launch_bounds__(256) void k_accadd(const float4* __restrict__ out,
                                                float4* __restrict__ acc,
                                                float scale, int n4) {
    int i = blockIdx.x * blockDim.x + threadIdx.x;
    if (i >= n4) return;
    float4 o = out[i];
    float4 a = acc[i];
    a.x = (a.x + o.x) * scale;
    a.y = (a.y + o.y) * scale;
    a.z = (a.z + o.z) * scale;
    a.w = (a.w + o.w) * scale;
    acc[i] = a;
}

extern "C" void kernel_launch(void* const* d_in, const int* in_sizes, int n_in,
                              void* d_out, int out_size, void* d_ws, size_t ws_size,
                              hipStream_t stream) {
    const int* ei      = (const int*)d_in[0];
    const float* uemb  = (const float*)d_in[1];
    const float* iemb  = (const float*)d_in[2];
    const float* Ws    = (const float*)d_in[3];
    const float* bs    = (const float*)d_in[4];

    const int E = in_sizes[0] / 2;
    const int U = in_sizes[1] / D;
    const int I = in_sizes[2] / D;
    const int N = U + I;
    const int L = in_sizes[3] / (D * D);
    const int ND = N * D;

    float* bufA = (float*)d_ws;          // [N, D]
    float* bufB = bufA + ND;             // [N, D]
    float* h    = bufB + ND;             // [N, D]
    float* dinv = h + ND;                // [N]
    int*   deg  = (int*)(dinv + N);      // [N]

    float* acc = (float*)d_out;          // [N, D] running sum, scaled at end

    hipMemsetAsync(deg, 0, N * sizeof(int), stream);
    k_count_deg<<<(E + 255) / 256, 256, 0, stream>>>(ei, deg, E);
    k_dinv<<<(N + 255) / 256, 256, 0, stream>>>(deg, dinv, N);
    k_init_x<<<2048, 256, 0, stream>>>((const float4*)uemb, (const float4*)iemb,
                                       (float4*)bufA, (float4*)acc,
                                       U * D / 4, ND / 4);

    float* x = bufA;
    float* out = bufB;
    for (int l = 0; l < L; ++l) {
        k_gemm<<<1024, 256, 0, stream>>>(x, Ws + (size_t)l * D * D, bs + (size_t)l * D,
                                         dinv, h, out, N);
        k_scatter<<<(E + 3) / 4, 256, 0, stream>>>(ei, h, dinv, out, E);
        k_accadd<<<(ND / 4 + 255) / 256, 256, 0, stream>>>((const float4*)out,
                                                           (float4*)acc,
                                                           (l == L - 1) ? 1.0f / (L + 1) : 1.0f,
                                                           ND / 4);
        float* t = x; x = out; out = t;
    }
}

// Round 2
// 971.298 us; speedup vs baseline: 2.1309x; 2.1309x over previous
//
#include <hip/hip_runtime.h>

constexpr int D = 64;
constexpr int SCAN_BLK = 1024;   // elements per scan block (256 thr x 4)

// ---------------- deg count (int atomics, once) ----------------
__global__ __launch_bounds__(256) void k_count_deg(const int* __restrict__ ei,
                                                   int* __restrict__ deg, int E) {
    int e = blockIdx.x * blockDim.x + threadIdx.x;
    if (e < E) atomicAdd(&deg[ei[E + e]], 1);   // dst row
}

__global__ __launch_bounds__(256) void k_dinv(const int* __restrict__ deg,
                                              float* __restrict__ dinv, int N) {
    int n = blockIdx.x * blockDim.x + threadIdx.x;
    if (n < N) dinv[n] = rsqrtf((float)(deg[n] + 1));  // +1 self-loop
}

// ---------------- exclusive scan of deg -> rowptr (3-kernel) ----------------
__global__ __launch_bounds__(256) void k_scan_reduce(const int* __restrict__ deg,
                                                     int* __restrict__ partials, int N) {
    __shared__ int sm[256];
    int base = blockIdx.x * SCAN_BLK + threadIdx.x * 4;
    int s = 0;
#pragma unroll
    for (int j = 0; j < 4; ++j) { int idx = base + j; if (idx < N) s += deg[idx]; }
    sm[threadIdx.x] = s;
    __syncthreads();
    for (int off = 128; off > 0; off >>= 1) {
        if (threadIdx.x < off) sm[threadIdx.x] += sm[threadIdx.x + off];
        __syncthreads();
    }
    if (threadIdx.x == 0) partials[blockIdx.x] = sm[0];
}

__global__ void k_scan_partials(int* __restrict__ partials, int nb,
                                int* __restrict__ rowptr, int N, int E) {
    if (threadIdx.x == 0) {
        int run = 0;
        for (int i = 0; i < nb; ++i) { int v = partials[i]; partials[i] = run; run += v; }
        rowptr[N] = E;
    }
}

__global__ __launch_bounds__(256) void k_scan_final(const int* __restrict__ deg,
                                                    const int* __restrict__ partials,
                                                    int* __restrict__ rowptr, int N) {
    __shared__ int sm[256];
    int base = blockIdx.x * SCAN_BLK + threadIdx.x * 4;
    int v0 = 0, v1 = 0, v2 = 0, v3 = 0;
    if (base + 0 < N) v0 = deg[base + 0];
    if (base + 1 < N) v1 = deg[base + 1];
    if (base + 2 < N) v2 = deg[base + 2];
    if (base + 3 < N) v3 = deg[base + 3];
    int s = v0 + v1 + v2 + v3;
    sm[threadIdx.x] = s;
    __syncthreads();
    // Hillis-Steele inclusive scan over 256 thread sums
    for (int off = 1; off < 256; off <<= 1) {
        int t = (threadIdx.x >= off) ? sm[threadIdx.x - off] : 0;
        __syncthreads();
        sm[threadIdx.x] += t;
        __syncthreads();
    }
    int off = partials[blockIdx.x] + sm[threadIdx.x] - s;  // exclusive
    if (base + 0 < N) rowptr[base + 0] = off;
    if (base + 1 < N) rowptr[base + 1] = off + v0;
    if (base + 2 < N) rowptr[base + 2] = off + v0 + v1;
    if (base + 3 < N) rowptr[base + 3] = off + v0 + v1 + v2;
}

// ---------------- counting-sort edges by dst ----------------
__global__ __launch_bounds__(256) void k_sort_edges(const int* __restrict__ ei,
                                                    const int* __restrict__ rowptr,
                                                    int* __restrict__ fill,
                                                    int* __restrict__ csr_src, int E) {
    int e = blockIdx.x * blockDim.x + threadIdx.x;
    if (e >= E) return;
    int src = ei[e];
    int dst = ei[E + e];
    int pos = rowptr[dst] + atomicAdd(&fill[dst], 1);
    csr_src[pos] = src;
}

// ---------------- init x = concat(u, it); acc = x ----------------
__global__ __launch_bounds__(256) void k_init_x(const float4* __restrict__ u,
                                                const float4* __restrict__ it,
                                                float4* __restrict__ x,
                                                float4* __restrict__ acc,
                                                int UD4, int total4) {
    int i = blockIdx.x * blockDim.x + threadIdx.x;
    int stride = gridDim.x * blockDim.x;
    for (; i < total4; i += stride) {
        float4 v = (i < UD4) ? u[i] : it[i - UD4];
        x[i] = v;
        acc[i] = v;
    }
}

// ---------------- in-place: x <- (x @ W) * dinv[row] ----------------
__global__ __launch_bounds__(256) void k_gemm_scaled(float* __restrict__ x,
                                                     const float* __restrict__ W,
                                                     const float* __restrict__ dinv,
                                                     int N) {
    __shared__ float Wl[D * D];
    for (int i = threadIdx.x; i < D * D; i += blockDim.x) Wl[i] = W[i];
    __syncthreads();

    const int lane = threadIdx.x & 63;
    const int wave = threadIdx.x >> 6;
    const int wavesTotal = gridDim.x * (blockDim.x >> 6);
    int row = blockIdx.x * (blockDim.x >> 6) + wave;

    for (; row < N; row += wavesTotal) {
        float xv = x[row * D + lane];
        float acc = 0.f;
#pragma unroll
        for (int k = 0; k < D; ++k) {
            float xk = __shfl(xv, k);
            acc = fmaf(xk, Wl[k * D + lane], acc);
        }
        x[row * D + lane] = acc * dinv[row];   // hs = h * dinv, in place
    }
}

// ------- aggregate: out[d] = dinv[d]*(hs[d] + sum_nbr hs[src]) + b; acc update -------
__global__ __launch_bounds__(256) void k_aggregate(const int* __restrict__ rowptr,
                                                   const int* __restrict__ csr_src,
                                                   const float* __restrict__ hs,
                                                   const float* __restrict__ dinv,
                                                   const float* __restrict__ b,
                                                   float* __restrict__ out,
                                                   float* __restrict__ acc,
                                                   float scale, int N) {
    int w = (int)((blockIdx.x * (size_t)blockDim.x + threadIdx.x) >> 6);
    int lane = threadIdx.x & 63;
    if (w >= N) return;
    int beg = rowptr[w], end = rowptr[w + 1];
    float s0 = hs[(size_t)w * D + lane];   // self-loop term (hs already * dinv[src])
    float s1 = 0.f, s2 = 0.f, s3 = 0.f;
    int e = beg;
    for (; e + 4 <= end; e += 4) {
        int i0 = csr_src[e + 0];
        int i1 = csr_src[e + 1];
        int i2 = csr_src[e + 2];
        int i3 = csr_src[e + 3];
        s0 += hs[(size_t)i0 * D + lane];
        s1 += hs[(size_t)i1 * D + lane];
        s2 += hs[(size_t)i2 * D + lane];
        s3 += hs[(size_t)i3 * D + lane];
    }
    for (; e < end; ++e) s0 += hs[(size_t)csr_src[e] * D + lane];
    float val = fmaf((s0 + s1) + (s2 + s3), dinv[w], b[lane]);
    size_t idx = (size_t)w * D + lane;
    out[idx] = val;
    acc[idx] = (acc[idx] + val) * scale;
}

extern "C" void kernel_launch(void* const* d_in, const int* in_sizes, int n_in,
                              void* d_out, int out_size, void* d_ws, size_t ws_size,
                              hipStream_t stream) {
    const int* ei      = (const int*)d_in[0];
    const float* uemb  = (const float*)d_in[1];
    const float* iemb  = (const float*)d_in[2];
    const float* Ws    = (const float*)d_in[3];
    const float* bs    = (const float*)d_in[4];

    const int E = in_sizes[0] / 2;
    const int U = in_sizes[1] / D;
    const int I = in_sizes[2] / D;
    const int N = U + I;
    const int L = in_sizes[3] / (D * D);
    const int ND = N * D;

    float* bufA    = (float*)d_ws;            // [N, D]  x / hs ping
    float* bufB    = bufA + ND;               // [N, D]  pong
    float* dinv    = bufB + ND;               // [N]
    int*   csr_src = (int*)(dinv + N);        // [E]
    int*   rowptr  = csr_src + E;             // [N+1]
    int*   deg     = rowptr + N + 1;          // [N]  (reused as fill)
    int*   partials= deg + N;                 // [nb]

    float* acc = (float*)d_out;               // [N, D] running sum

    const int nb = (N + SCAN_BLK - 1) / SCAN_BLK;

    // build CSR (by dst)
    hipMemsetAsync(deg, 0, N * sizeof(int), stream);
    k_count_deg<<<(E + 255) / 256, 256, 0, stream>>>(ei, deg, E);
    k_dinv<<<(N + 255) / 256, 256, 0, stream>>>(deg, dinv, N);
    k_scan_reduce<<<nb, 256, 0, stream>>>(deg, partials, N);
    k_scan_partials<<<1, 64, 0, stream>>>(partials, nb, rowptr, N, E);
    k_scan_final<<<nb, 256, 0, stream>>>(deg, partials, rowptr, N);
    hipMemsetAsync(deg, 0, N * sizeof(int), stream);   // reuse as fill
    k_sort_edges<<<(E + 255) / 256, 256, 0, stream>>>(ei, rowptr, deg, csr_src, E);

    // x0, acc init
    k_init_x<<<2048, 256, 0, stream>>>((const float4*)uemb, (const float4*)iemb,
                                       (float4*)bufA, (float4*)acc,
                                       U * D / 4, ND / 4);

    float* x = bufA;
    float* out = bufB;
    for (int l = 0; l < L; ++l) {
        k_gemm_scaled<<<1024, 256, 0, stream>>>(x, Ws + (size_t)l * D * D, dinv, N);
        k_aggregate<<<(N + 3) / 4, 256, 0, stream>>>(rowptr, csr_src, x, dinv,
                                                     bs + (size_t)l * D, out, acc,
                                                     (l == L - 1) ? 1.0f / (L + 1) : 1.0f, N);
        float* t = x; x = out; out = t;
    }
}

// Round 3
// 937.924 us; speedup vs baseline: 2.2067x; 1.0356x over previous
//
#include <hip/hip_runtime.h>

constexpr int D = 64;
constexpr int SCAN_BLK = 1024;   // elements per scan block (256 thr x 4)

__device__ inline unsigned short f2bf(float f) {   // RNE f32->bf16
    unsigned int u = __float_as_uint(f);
    u += 0x7FFFu + ((u >> 16) & 1u);
    return (unsigned short)(u >> 16);
}
__device__ inline float bf2f(unsigned short s) {   // exact bf16->f32
    return __uint_as_float(((unsigned int)s) << 16);
}

// ---------------- deg count (int atomics, once) ----------------
__global__ __launch_bounds__(256) void k_count_deg(const int* __restrict__ ei,
                                                   int* __restrict__ deg, int E) {
    int e = blockIdx.x * blockDim.x + threadIdx.x;
    if (e < E) atomicAdd(&deg[ei[E + e]], 1);   // dst row
}

__global__ __launch_bounds__(256) void k_dinv(const int* __restrict__ deg,
                                              float* __restrict__ dinv, int N) {
    int n = blockIdx.x * blockDim.x + threadIdx.x;
    if (n < N) dinv[n] = rsqrtf((float)(deg[n] + 1));  // +1 self-loop
}

// ---------------- exclusive scan of deg -> rowptr (3-kernel) ----------------
__global__ __launch_bounds__(256) void k_scan_reduce(const int* __restrict__ deg,
                                                     int* __restrict__ partials, int N) {
    __shared__ int sm[256];
    int base = blockIdx.x * SCAN_BLK + threadIdx.x * 4;
    int s = 0;
#pragma unroll
    for (int j = 0; j < 4; ++j) { int idx = base + j; if (idx < N) s += deg[idx]; }
    sm[threadIdx.x] = s;
    __syncthreads();
    for (int off = 128; off > 0; off >>= 1) {
        if (threadIdx.x < off) sm[threadIdx.x] += sm[threadIdx.x + off];
        __syncthreads();
    }
    if (threadIdx.x == 0) partials[blockIdx.x] = sm[0];
}

__global__ void k_scan_partials(int* __restrict__ partials, int nb,
                                int* __restrict__ rowptr, int N, int E) {
    if (threadIdx.x == 0) {
        int run = 0;
        for (int i = 0; i < nb; ++i) { int v = partials[i]; partials[i] = run; run += v; }
        rowptr[N] = E;
    }
}

__global__ __launch_bounds__(256) void k_scan_final(const int* __restrict__ deg,
                                                    const int* __restrict__ partials,
                                                    int* __restrict__ rowptr, int N) {
    __shared__ int sm[256];
    int base = blockIdx.x * SCAN_BLK + threadIdx.x * 4;
    int v0 = 0, v1 = 0, v2 = 0, v3 = 0;
    if (base + 0 < N) v0 = deg[base + 0];
    if (base + 1 < N) v1 = deg[base + 1];
    if (base + 2 < N) v2 = deg[base + 2];
    if (base + 3 < N) v3 = deg[base + 3];
    int s = v0 + v1 + v2 + v3;
    sm[threadIdx.x] = s;
    __syncthreads();
    for (int off = 1; off < 256; off <<= 1) {
        int t = (threadIdx.x >= off) ? sm[threadIdx.x - off] : 0;
        __syncthreads();
        sm[threadIdx.x] += t;
        __syncthreads();
    }
    int off = partials[blockIdx.x] + sm[threadIdx.x] - s;  // exclusive
    if (base + 0 < N) rowptr[base + 0] = off;
    if (base + 1 < N) rowptr[base + 1] = off + v0;
    if (base + 2 < N) rowptr[base + 2] = off + v0 + v1;
    if (base + 3 < N) rowptr[base + 3] = off + v0 + v1 + v2;
}

// ---------------- counting-sort edges by dst ----------------
__global__ __launch_bounds__(256) void k_sort_edges(const int* __restrict__ ei,
                                                    const int* __restrict__ rowptr,
                                                    int* __restrict__ fill,
                                                    int* __restrict__ csr_src, int E) {
    int e = blockIdx.x * blockDim.x + threadIdx.x;
    if (e >= E) return;
    int src = ei[e];
    int dst = ei[E + e];
    int pos = rowptr[dst] + atomicAdd(&fill[dst], 1);
    csr_src[pos] = src;
}

// ---------------- acc = concat(u, it) ----------------
__global__ __launch_bounds__(256) void k_init_acc(const float4* __restrict__ u,
                                                  const float4* __restrict__ it,
                                                  float4* __restrict__ acc,
                                                  int UD4, int total4) {
    int i = blockIdx.x * blockDim.x + threadIdx.x;
    int stride = gridDim.x * blockDim.x;
    for (; i < total4; i += stride)
        acc[i] = (i < UD4) ? u[i] : it[i - UD4];
}

// ------- hs16[row] = bf16( (x @ W)[row] * dinv[row] ) ; x may be concat(u,it) -------
__global__ __launch_bounds__(256) void k_gemm_scaled(const float* __restrict__ x,
                                                     const float* __restrict__ u,
                                                     const float* __restrict__ it,
                                                     int U,
                                                     const float* __restrict__ W,
                                                     const float* __restrict__ dinv,
                                                     unsigned short* __restrict__ hs16,
                                                     int N) {
    __shared__ float Wl[D * D];
    for (int i = threadIdx.x; i < D * D; i += blockDim.x) Wl[i] = W[i];
    __syncthreads();

    const int lane = threadIdx.x & 63;
    const int wave = threadIdx.x >> 6;
    const int wavesTotal = gridDim.x * (blockDim.x >> 6);
    int row = blockIdx.x * (blockDim.x >> 6) + wave;

    for (; row < N; row += wavesTotal) {
        float xv;
        if (x) xv = x[(size_t)row * D + lane];
        else   xv = (row < U) ? u[(size_t)row * D + lane]
                              : it[(size_t)(row - U) * D + lane];
        float acc = 0.f;
#pragma unroll
        for (int k = 0; k < D; ++k) {
            float xk = __shfl(xv, k);
            acc = fmaf(xk, Wl[k * D + lane], acc);
        }
        hs16[(size_t)row * D + lane] = f2bf(acc * dinv[row]);
    }
}

// ------- out[d] = dinv[d]*(hs[d] + sum_nbr hs[src]) + b; acc = (acc+out)*scale -------
__global__ __launch_bounds__(256) void k_aggregate(const int* __restrict__ rowptr,
                                                   const int* __restrict__ csr_src,
                                                   const unsigned short* __restrict__ hs16,
                                                   const float* __restrict__ dinv,
                                                   const float* __restrict__ b,
                                                   float* __restrict__ out,
                                                   float* __restrict__ acc,
                                                   float scale, int N) {
    int w = (int)((blockIdx.x * (size_t)blockDim.x + threadIdx.x) >> 6);
    int lane = threadIdx.x & 63;
    if (w >= N) return;
    int beg = rowptr[w], end = rowptr[w + 1];
    float s0 = bf2f(hs16[(size_t)w * D + lane]);   // self-loop (already * dinv)
    float s1 = 0.f, s2 = 0.f, s3 = 0.f;
    int e = beg;
    for (; e + 4 <= end; e += 4) {
        int i0 = csr_src[e + 0];
        int i1 = csr_src[e + 1];
        int i2 = csr_src[e + 2];
        int i3 = csr_src[e + 3];
        s0 += bf2f(hs16[(size_t)i0 * D + lane]);
        s1 += bf2f(hs16[(size_t)i1 * D + lane]);
        s2 += bf2f(hs16[(size_t)i2 * D + lane]);
        s3 += bf2f(hs16[(size_t)i3 * D + lane]);
    }
    for (; e < end; ++e) s0 += bf2f(hs16[(size_t)csr_src[e] * D + lane]);
    float val = fmaf((s0 + s1) + (s2 + s3), dinv[w], b[lane]);
    size_t idx = (size_t)w * D + lane;
    out[idx] = val;
    acc[idx] = (acc[idx] + val) * scale;
}

extern "C" void kernel_launch(void* const* d_in, const int* in_sizes, int n_in,
                              void* d_out, int out_size, void* d_ws, size_t ws_size,
                              hipStream_t stream) {
    const int* ei      = (const int*)d_in[0];
    const float* uemb  = (const float*)d_in[1];
    const float* iemb  = (const float*)d_in[2];
    const float* Ws    = (const float*)d_in[3];
    const float* bs    = (const float*)d_in[4];

    const int E = in_sizes[0] / 2;
    const int U = in_sizes[1] / D;
    const int I = in_sizes[2] / D;
    const int N = U + I;
    const int L = in_sizes[3] / (D * D);
    const int ND = N * D;

    float* bufA    = (float*)d_ws;                    // [N, D] f32 ping
    float* bufB    = bufA + ND;                       // [N, D] f32 pong
    unsigned short* hs16 = (unsigned short*)(bufB + ND); // [N, D] bf16
    float* dinv    = (float*)(hs16 + ND);             // [N]
    int*   csr_src = (int*)(dinv + N);                // [E]
    int*   rowptr  = csr_src + E;                     // [N+1]
    int*   deg     = rowptr + N + 1;                  // [N] (reused as fill)
    int*   partials= deg + N;                         // [nb]

    float* acc = (float*)d_out;                       // [N, D] running sum

    const int nb = (N + SCAN_BLK - 1) / SCAN_BLK;

    // build CSR (by dst)
    hipMemsetAsync(deg, 0, N * sizeof(int), stream);
    k_count_deg<<<(E + 255) / 256, 256, 0, stream>>>(ei, deg, E);
    k_dinv<<<(N + 255) / 256, 256, 0, stream>>>(deg, dinv, N);
    k_scan_reduce<<<nb, 256, 0, stream>>>(deg, partials, N);
    k_scan_partials<<<1, 64, 0, stream>>>(partials, nb, rowptr, N, E);
    k_scan_final<<<nb, 256, 0, stream>>>(deg, partials, rowptr, N);
    hipMemsetAsync(deg, 0, N * sizeof(int), stream);   // reuse as fill
    k_sort_edges<<<(E + 255) / 256, 256, 0, stream>>>(ei, rowptr, deg, csr_src, E);

    // acc = x0
    k_init_acc<<<2048, 256, 0, stream>>>((const float4*)uemb, (const float4*)iemb,
                                         (float4*)acc, U * D / 4, ND / 4);

    const float* xin = nullptr;   // layer 0 reads emb directly
    float* xout = bufA;
    for (int l = 0; l < L; ++l) {
        k_gemm_scaled<<<1024, 256, 0, stream>>>(xin, uemb, iemb, U,
                                                Ws + (size_t)l * D * D, dinv, hs16, N);
        k_aggregate<<<(N + 3) / 4, 256, 0, stream>>>(rowptr, csr_src, hs16, dinv,
                                                     bs + (size_t)l * D, xout, acc,
                                                     (l == L - 1) ? 1.0f / (L + 1) : 1.0f, N);
        xin = xout;
        xout = (xout == bufA) ? bufB : bufA;
    }
}

// Round 4
// 751.793 us; speedup vs baseline: 2.7531x; 1.2476x over previous
//
#include <hip/hip_runtime.h>

constexpr int D = 64;
constexpr int BUK_SHIFT = 9;            // 512 dst nodes per bucket
constexpr int BUK_NODES = 1 << BUK_SHIFT;
constexpr int MAX_NBUK = 320;           // supports N <= 163840
constexpr int TILE_E = 4096;            // edges per scatter block (512 thr x 8)

__device__ inline unsigned short f2bf(float f) {   // RNE f32->bf16
    unsigned int u = __float_as_uint(f);
    u += 0x7FFFu + ((u >> 16) & 1u);
    return (unsigned short)(u >> 16);
}
__device__ inline float bf2f(unsigned short s) {
    return __uint_as_float(((unsigned int)s) << 16);
}

// ---------- 1. histogram of coarse buckets (dst >> BUK_SHIFT) ----------
__global__ __launch_bounds__(256) void k_bucket_hist(const int* __restrict__ ei,
                                                     int* __restrict__ bcount,
                                                     int E, int nbuk) {
    __shared__ int h[MAX_NBUK];
    for (int i = threadIdx.x; i < nbuk; i += blockDim.x) h[i] = 0;
    __syncthreads();
    int stride = gridDim.x * blockDim.x;
    for (int e = blockIdx.x * blockDim.x + threadIdx.x; e < E; e += stride)
        atomicAdd(&h[ei[E + e] >> BUK_SHIFT], 1);
    __syncthreads();
    for (int i = threadIdx.x; i < nbuk; i += blockDim.x)
        if (h[i]) atomicAdd(&bcount[i], h[i]);
}

// ---------- 2. scan bucket counts -> bbase; zero gfill; rowptr[N]=E ----------
__global__ __launch_bounds__(512) void k_scan_buckets(const int* __restrict__ bcount,
                                                      int* __restrict__ bbase,
                                                      int* __restrict__ gfill,
                                                      int* __restrict__ rowptr,
                                                      int nbuk, int N, int E) {
    __shared__ int sc[512];
    int tid = threadIdx.x;
    int v = (tid < nbuk) ? bcount[tid] : 0;
    sc[tid] = v;
    __syncthreads();
    for (int off = 1; off < 512; off <<= 1) {
        int t = (tid >= off) ? sc[tid - off] : 0;
        __syncthreads();
        sc[tid] += t;
        __syncthreads();
    }
    if (tid < nbuk) { bbase[tid] = sc[tid] - v; gfill[tid] = 0; }
    if (tid == 0) { bbase[nbuk] = E; rowptr[N] = E; }
}

// ---------- 3. scatter edges into coarse buckets (packed u32) ----------
// packed = (local_dst << 18) | src   (src < 2^18, local_dst < 512)
__global__ __launch_bounds__(512) void k_bucket_scatter(const int* __restrict__ ei,
                                                        const int* __restrict__ bbase,
                                                        int* __restrict__ gfill,
                                                        unsigned int* __restrict__ packed,
                                                        int E, int nbuk) {
    __shared__ int hist[MAX_NBUK], base[MAX_NBUK], fil[MAX_NBUK];
    const int tid = threadIdx.x;
    for (int i = tid; i < nbuk; i += 512) hist[i] = 0;
    __syncthreads();

    const int t0 = blockIdx.x * TILE_E;
    int bk[8];
    unsigned int vv[8];
#pragma unroll
    for (int j = 0; j < 8; ++j) {
        int e = t0 + tid + j * 512;
        bk[j] = -1;
        if (e < E) {
            int src = ei[e];
            int dst = ei[E + e];
            bk[j] = dst >> BUK_SHIFT;
            vv[j] = ((unsigned int)(dst & (BUK_NODES - 1)) << 18) | (unsigned int)src;
            atomicAdd(&hist[bk[j]], 1);
        }
    }
    __syncthreads();
    for (int i = tid; i < nbuk; i += 512) {
        if (hist[i]) base[i] = atomicAdd(&gfill[i], hist[i]);
        fil[i] = 0;
    }
    __syncthreads();
#pragma unroll
    for (int j = 0; j < 8; ++j) {
        if (bk[j] >= 0) {
            int b = bk[j];
            int pos = bbase[b] + base[b] + atomicAdd(&fil[b], 1);
            packed[pos] = vv[j];
        }
    }
}

// ---------- 4. per-bucket: local hist -> rowptr, dinv, ordered csr_src ----------
__global__ __launch_bounds__(256) void k_build_csr(const unsigned int* __restrict__ packed,
                                                   const int* __restrict__ bbase,
                                                   int* __restrict__ rowptr,
                                                   float* __restrict__ dinv,
                                                   int* __restrict__ csr_src,
                                                   int N) {
    __shared__ int hist[BUK_NODES], rp[BUK_NODES], fil[BUK_NODES];
    const int b = blockIdx.x;
    const int s = bbase[b], t = bbase[b + 1];
    const int tid = threadIdx.x;
    for (int i = tid; i < BUK_NODES; i += 256) hist[i] = 0;
    __syncthreads();
    for (int e = s + tid; e < t; e += 256)
        atomicAdd(&hist[packed[e] >> 18], 1);
    __syncthreads();
    if (tid == 0) {
        int run = 0;
        for (int i = 0; i < BUK_NODES; ++i) { rp[i] = run; run += hist[i]; }
    }
    __syncthreads();
    const int dbase = b << BUK_SHIFT;
    for (int ld = tid; ld < BUK_NODES; ld += 256) {
        int d = dbase + ld;
        if (d < N) {
            rowptr[d] = s + rp[ld];
            dinv[d] = rsqrtf((float)(hist[ld] + 1));   // +1 self-loop
        }
        fil[ld] = 0;
    }
    __syncthreads();
    for (int e = s + tid; e < t; e += 256) {
        unsigned int v = packed[e];
        int ld = v >> 18;
        int pos = s + rp[ld] + atomicAdd(&fil[ld], 1);
        csr_src[pos] = (int)(v & 0x3FFFFu);
    }
}

// ---------------- acc = concat(u, it) ----------------
__global__ __launch_bounds__(256) void k_init_acc(const float4* __restrict__ u,
                                                  const float4* __restrict__ it,
                                                  float4* __restrict__ acc,
                                                  int UD4, int total4) {
    int i = blockIdx.x * blockDim.x + threadIdx.x;
    int stride = gridDim.x * blockDim.x;
    for (; i < total4; i += stride)
        acc[i] = (i < UD4) ? u[i] : it[i - UD4];
}

// ------- hs16[row] = bf16( (x @ W)[row] * dinv[row] ) -------
__global__ __launch_bounds__(256) void k_gemm_scaled(const float* __restrict__ x,
                                                     const float* __restrict__ u,
                                                     const float* __restrict__ it,
                                                     int U,
                                                     const float* __restrict__ W,
                                                     const float* __restrict__ dinv,
                                                     unsigned short* __restrict__ hs16,
                                                     int N) {
    __shared__ float Wl[D * D];
    for (int i = threadIdx.x; i < D * D; i += blockDim.x) Wl[i] = W[i];
    __syncthreads();

    const int lane = threadIdx.x & 63;
    const int wave = threadIdx.x >> 6;
    const int wavesTotal = gridDim.x * (blockDim.x >> 6);
    int row = blockIdx.x * (blockDim.x >> 6) + wave;

    for (; row < N; row += wavesTotal) {
        float xv;
        if (x) xv = x[(size_t)row * D + lane];
        else   xv = (row < U) ? u[(size_t)row * D + lane]
                              : it[(size_t)(row - U) * D + lane];
        float acc = 0.f;
#pragma unroll
        for (int k = 0; k < D; ++k) {
            float xk = __shfl(xv, k);
            acc = fmaf(xk, Wl[k * D + lane], acc);
        }
        hs16[(size_t)row * D + lane] = f2bf(acc * dinv[row]);
    }
}

// ------- out[d] = dinv[d]*(hs[d] + sum_nbr hs[src]) + b; acc = (acc+out)*scale -------
__global__ __launch_bounds__(256) void k_aggregate(const int* __restrict__ rowptr,
                                                   const int* __restrict__ csr_src,
                                                   const unsigned short* __restrict__ hs16,
                                                   const float* __restrict__ dinv,
                                                   const float* __restrict__ b,
                                                   float* __restrict__ out,
                                                   float* __restrict__ acc,
                                                   float scale, int N) {
    int w = (int)((blockIdx.x * (size_t)blockDim.x + threadIdx.x) >> 6);
    int lane = threadIdx.x & 63;
    if (w >= N) return;
    int beg = rowptr[w], end = rowptr[w + 1];
    float s0 = bf2f(hs16[(size_t)w * D + lane]);   // self-loop (already * dinv)
    float s1 = 0.f, s2 = 0.f, s3 = 0.f;
    int e = beg;
    for (; e + 4 <= end; e += 4) {
        int i0 = csr_src[e + 0];
        int i1 = csr_src[e + 1];
        int i2 = csr_src[e + 2];
        int i3 = csr_src[e + 3];
        s0 += bf2f(hs16[(size_t)i0 * D + lane]);
        s1 += bf2f(hs16[(size_t)i1 * D + lane]);
        s2 += bf2f(hs16[(size_t)i2 * D + lane]);
        s3 += bf2f(hs16[(size_t)i3 * D + lane]);
    }
    for (; e < end; ++e) s0 += bf2f(hs16[(size_t)csr_src[e] * D + lane]);
    float val = fmaf((s0 + s1) + (s2 + s3), dinv[w], b[lane]);
    size_t idx = (size_t)w * D + lane;
    out[idx] = val;
    acc[idx] = (acc[idx] + val) * scale;
}

extern "C" void kernel_launch(void* const* d_in, const int* in_sizes, int n_in,
                              void* d_out, int out_size, void* d_ws, size_t ws_size,
                              hipStream_t stream) {
    const int* ei      = (const int*)d_in[0];
    const float* uemb  = (const float*)d_in[1];
    const float* iemb  = (const float*)d_in[2];
    const float* Ws    = (const float*)d_in[3];
    const float* bs    = (const float*)d_in[4];

    const int E = in_sizes[0] / 2;
    const int U = in_sizes[1] / D;
    const int I = in_sizes[2] / D;
    const int N = U + I;
    const int L = in_sizes[3] / (D * D);
    const int ND = N * D;
    const int nbuk = (N + BUK_NODES - 1) >> BUK_SHIFT;

    float* buf     = (float*)d_ws;                       // [N, D] f32 (x ping)
    unsigned short* hs16 = (unsigned short*)(buf + ND);  // [N, D] bf16
    float* dinv    = (float*)(hs16 + ND);                // [N]
    int*   csr_src = (int*)(dinv + N);                   // [E]
    unsigned int* packed = (unsigned int*)(csr_src + E); // [E]
    int*   rowptr  = (int*)(packed + E);                 // [N+1]
    int*   bcount  = rowptr + N + 1;                     // [nbuk]
    int*   bbase   = bcount + MAX_NBUK;                  // [nbuk+1]
    int*   gfill   = bbase + MAX_NBUK + 1;               // [nbuk]

    float* acc = (float*)d_out;                          // [N, D]

    // ---- build CSR ----
    hipMemsetAsync(bcount, 0, nbuk * sizeof(int), stream);
    k_bucket_hist<<<512, 256, 0, stream>>>(ei, bcount, E, nbuk);
    k_scan_buckets<<<1, 512, 0, stream>>>(bcount, bbase, gfill, rowptr, nbuk, N, E);
    k_bucket_scatter<<<(E + TILE_E - 1) / TILE_E, 512, 0, stream>>>(ei, bbase, gfill,
                                                                   packed, E, nbuk);
    k_build_csr<<<nbuk, 256, 0, stream>>>(packed, bbase, rowptr, dinv, csr_src, N);

    // ---- acc = x0 ----
    k_init_acc<<<2048, 256, 0, stream>>>((const float4*)uemb, (const float4*)iemb,
                                         (float4*)acc, U * D / 4, ND / 4);

    // ---- layers ----
    const float* xin = nullptr;   // layer 0 reads emb directly
    for (int l = 0; l < L; ++l) {
        k_gemm_scaled<<<1024, 256, 0, stream>>>(xin, uemb, iemb, U,
                                                Ws + (size_t)l * D * D, dinv, hs16, N);
        k_aggregate<<<(N + 3) / 4, 256, 0, stream>>>(rowptr, csr_src, hs16, dinv,
                                                     bs + (size_t)l * D, buf, acc,
                                                     (l == L - 1) ? 1.0f / (L + 1) : 1.0f, N);
        xin = buf;
    }
}

// Round 5
// 438.338 us; speedup vs baseline: 4.7218x; 1.7151x over previous
//
#include <hip/hip_runtime.h>

constexpr int D = 64;
constexpr int BUK_SHIFT = 9;            // 512 dst nodes per bucket
constexpr int BUK_NODES = 1 << BUK_SHIFT;
constexpr int MAX_NBUK = 320;           // supports N <= 163840
constexpr int TILE_E = 4096;            // edges per scatter block (512 thr x 8)

typedef __attribute__((ext_vector_type(8))) short short8;   // 8 bf16 (4 VGPRs)
typedef __attribute__((ext_vector_type(4))) float f32x4;

__device__ inline unsigned short f2bf(float f) {   // RNE f32->bf16
    unsigned int u = __float_as_uint(f);
    u += 0x7FFFu + ((u >> 16) & 1u);
    return (unsigned short)(u >> 16);
}
__device__ inline float bf2f(unsigned short s) {
    return __uint_as_float(((unsigned int)s) << 16);
}

// ---------- 1. histogram of coarse buckets (dst >> BUK_SHIFT) ----------
__global__ __launch_bounds__(256) void k_bucket_hist(const int* __restrict__ ei,
                                                     int* __restrict__ bcount,
                                                     int E, int nbuk) {
    __shared__ int h[MAX_NBUK];
    for (int i = threadIdx.x; i < nbuk; i += blockDim.x) h[i] = 0;
    __syncthreads();
    int stride = gridDim.x * blockDim.x;
    for (int e = blockIdx.x * blockDim.x + threadIdx.x; e < E; e += stride)
        atomicAdd(&h[ei[E + e] >> BUK_SHIFT], 1);
    __syncthreads();
    for (int i = threadIdx.x; i < nbuk; i += blockDim.x)
        if (h[i]) atomicAdd(&bcount[i], h[i]);
}

// ---------- 2. scan bucket counts -> bbase; zero gfill; rowptr[N]=E ----------
__global__ __launch_bounds__(512) void k_scan_buckets(const int* __restrict__ bcount,
                                                      int* __restrict__ bbase,
                                                      int* __restrict__ gfill,
                                                      int* __restrict__ rowptr,
                                                      int nbuk, int N, int E) {
    __shared__ int sc[512];
    int tid = threadIdx.x;
    int v = (tid < nbuk) ? bcount[tid] : 0;
    sc[tid] = v;
    __syncthreads();
    for (int off = 1; off < 512; off <<= 1) {
        int t = (tid >= off) ? sc[tid - off] : 0;
        __syncthreads();
        sc[tid] += t;
        __syncthreads();
    }
    if (tid < nbuk) { bbase[tid] = sc[tid] - v; gfill[tid] = 0; }
    if (tid == 0) { bbase[nbuk] = E; rowptr[N] = E; }
}

// ---------- 3. scatter edges into coarse buckets (packed u32) ----------
__global__ __launch_bounds__(512) void k_bucket_scatter(const int* __restrict__ ei,
                                                        const int* __restrict__ bbase,
                                                        int* __restrict__ gfill,
                                                        unsigned int* __restrict__ packed,
                                                        int E, int nbuk) {
    __shared__ int hist[MAX_NBUK], base[MAX_NBUK], fil[MAX_NBUK];
    const int tid = threadIdx.x;
    for (int i = tid; i < nbuk; i += 512) hist[i] = 0;
    __syncthreads();

    const int t0 = blockIdx.x * TILE_E;
    int bk[8];
    unsigned int vv[8];
#pragma unroll
    for (int j = 0; j < 8; ++j) {
        int e = t0 + tid + j * 512;
        bk[j] = -1;
        if (e < E) {
            int src = ei[e];
            int dst = ei[E + e];
            bk[j] = dst >> BUK_SHIFT;
            vv[j] = ((unsigned int)(dst & (BUK_NODES - 1)) << 18) | (unsigned int)src;
            atomicAdd(&hist[bk[j]], 1);
        }
    }
    __syncthreads();
    for (int i = tid; i < nbuk; i += 512) {
        if (hist[i]) base[i] = atomicAdd(&gfill[i], hist[i]);
        fil[i] = 0;
    }
    __syncthreads();
#pragma unroll
    for (int j = 0; j < 8; ++j) {
        if (bk[j] >= 0) {
            int b = bk[j];
            int pos = bbase[b] + base[b] + atomicAdd(&fil[b], 1);
            packed[pos] = vv[j];
        }
    }
}

// ---------- 4. per-bucket: local hist -> rowptr, dinv, ordered csr_src ----------
__global__ __launch_bounds__(256) void k_build_csr(const unsigned int* __restrict__ packed,
                                                   const int* __restrict__ bbase,
                                                   int* __restrict__ rowptr,
                                                   float* __restrict__ dinv,
                                                   int* __restrict__ csr_src,
                                                   int N) {
    __shared__ int hist[BUK_NODES], rp[BUK_NODES], fil[BUK_NODES];
    const int b = blockIdx.x;
    const int s = bbase[b], t = bbase[b + 1];
    const int tid = threadIdx.x;
    for (int i = tid; i < BUK_NODES; i += 256) hist[i] = 0;
    __syncthreads();
    for (int e = s + tid; e < t; e += 256)
        atomicAdd(&hist[packed[e] >> 18], 1);
    __syncthreads();
    if (tid == 0) {
        int run = 0;
        for (int i = 0; i < BUK_NODES; ++i) { rp[i] = run; run += hist[i]; }
    }
    __syncthreads();
    const int dbase = b << BUK_SHIFT;
    for (int ld = tid; ld < BUK_NODES; ld += 256) {
        int d = dbase + ld;
        if (d < N) {
            rowptr[d] = s + rp[ld];
            dinv[d] = rsqrtf((float)(hist[ld] + 1));   // +1 self-loop
        }
        fil[ld] = 0;
    }
    __syncthreads();
    for (int e = s + tid; e < t; e += 256) {
        unsigned int v = packed[e];
        int ld = v >> 18;
        int pos = s + rp[ld] + atomicAdd(&fil[ld], 1);
        csr_src[pos] = (int)(v & 0x3FFFFu);
    }
}

// ---------------- acc = concat(u, it) ----------------
__global__ __launch_bounds__(256) void k_init_acc(const float4* __restrict__ u,
                                                  const float4* __restrict__ it,
                                                  float4* __restrict__ acc,
                                                  int UD4, int total4) {
    int i = blockIdx.x * blockDim.x + threadIdx.x;
    int stride = gridDim.x * blockDim.x;
    for (; i < total4; i += stride)
        acc[i] = (i < UD4) ? u[i] : it[i - UD4];
}

// ------- MFMA: hs16[row] = bf16( (x @ W)[row] * dinv[row] ) -------
// wave handles 16 rows x 64 cols. A/B frag layout (16x16x32 bf16):
//   elems 0..3: k = kb*32 +      (lane>>4)*4 + e
//   elems 4..7: k = kb*32 + 16 + (lane>>4)*4 + e
// D: col = lane&15, row = (lane>>4)*4 + reg.
__global__ __launch_bounds__(256) void k_gemm_mfma(const float* __restrict__ x,
                                                   const float* __restrict__ u,
                                                   const float* __restrict__ it,
                                                   int U,
                                                   const float* __restrict__ W,
                                                   const float* __restrict__ dinv,
                                                   unsigned short* __restrict__ hs16,
                                                   int N) {
    const int lane = threadIdx.x & 63;
    const int g = lane >> 4;
    const int lr = lane & 15;

    // B frags: [col-tile][k-half], held in VGPRs for the wave's lifetime
    short8 bf[4][2];
#pragma unroll
    for (int ct = 0; ct < 4; ++ct)
#pragma unroll
        for (int kb = 0; kb < 2; ++kb) {
            short8 v;
            int c = ct * 16 + lr;
#pragma unroll
            for (int e = 0; e < 4; ++e) {
                int k0 = kb * 32 + g * 4 + e;
                int k1 = k0 + 16;
                v[e]     = (short)f2bf(W[k0 * D + c]);
                v[e + 4] = (short)f2bf(W[k1 * D + c]);
            }
            bf[ct][kb] = v;
        }

    const int wid = blockIdx.x * (blockDim.x >> 6) + (threadIdx.x >> 6);
    const int nw = gridDim.x * (blockDim.x >> 6);

    for (int rb = wid * 16; rb < N; rb += nw * 16) {
        int row = rb + lr;                     // A-operand row for this lane
        bool ok = (row < N);
        const float* xr = nullptr;
        if (ok) {
            if (x) xr = x + (size_t)row * D;
            else   xr = (row < U) ? (u + (size_t)row * D)
                                  : (it + (size_t)(row - U) * D);
        }
        short8 af[2];
#pragma unroll
        for (int kb = 0; kb < 2; ++kb) {
            float4 q0 = ok ? *(const float4*)(xr + kb * 32 + g * 4)
                           : float4{0.f, 0.f, 0.f, 0.f};
            float4 q1 = ok ? *(const float4*)(xr + kb * 32 + 16 + g * 4)
                           : float4{0.f, 0.f, 0.f, 0.f};
            short8 v;
            v[0] = (short)f2bf(q0.x); v[1] = (short)f2bf(q0.y);
            v[2] = (short)f2bf(q0.z); v[3] = (short)f2bf(q0.w);
            v[4] = (short)f2bf(q1.x); v[5] = (short)f2bf(q1.y);
            v[6] = (short)f2bf(q1.z); v[7] = (short)f2bf(q1.w);
            af[kb] = v;
        }

        float di[4];
#pragma unroll
        for (int r = 0; r < 4; ++r) {
            int ro = rb + g * 4 + r;
            di[r] = (ro < N) ? dinv[ro] : 0.f;
        }

#pragma unroll
        for (int ct = 0; ct < 4; ++ct) {
            f32x4 a = {0.f, 0.f, 0.f, 0.f};
            a = __builtin_amdgcn_mfma_f32_16x16x32_bf16(af[0], bf[ct][0], a, 0, 0, 0);
            a = __builtin_amdgcn_mfma_f32_16x16x32_bf16(af[1], bf[ct][1], a, 0, 0, 0);
#pragma unroll
            for (int r = 0; r < 4; ++r) {
                int ro = rb + g * 4 + r;
                if (ro < N)
                    hs16[(size_t)ro * D + ct * 16 + lr] = f2bf(a[r] * di[r]);
            }
        }
    }
}

// ------- out[d] = dinv[d]*(hs[d] + sum_nbr hs[src]) + b; acc = (acc+out)*scale -------
__global__ __launch_bounds__(256) void k_aggregate(const int* __restrict__ rowptr,
                                                   const int* __restrict__ csr_src,
                                                   const unsigned short* __restrict__ hs16,
                                                   const float* __restrict__ dinv,
                                                   const float* __restrict__ b,
                                                   float* __restrict__ out,
                                                   float* __restrict__ acc,
                                                   float scale, int N) {
    int w = (int)((blockIdx.x * (size_t)blockDim.x + threadIdx.x) >> 6);
    int lane = threadIdx.x & 63;
    if (w >= N) return;
    int beg = rowptr[w], end = rowptr[w + 1];
    float s0 = bf2f(hs16[(size_t)w * D + lane]);   // self-loop (already * dinv)
    float s1 = 0.f, s2 = 0.f, s3 = 0.f;
    int e = beg;
    for (; e + 4 <= end; e += 4) {
        int i0 = csr_src[e + 0];
        int i1 = csr_src[e + 1];
        int i2 = csr_src[e + 2];
        int i3 = csr_src[e + 3];
        s0 += bf2f(hs16[(size_t)i0 * D + lane]);
        s1 += bf2f(hs16[(size_t)i1 * D + lane]);
        s2 += bf2f(hs16[(size_t)i2 * D + lane]);
        s3 += bf2f(hs16[(size_t)i3 * D + lane]);
    }
    for (; e < end; ++e) s0 += bf2f(hs16[(size_t)csr_src[e] * D + lane]);
    float val = fmaf((s0 + s1) + (s2 + s3), dinv[w], b[lane]);
    size_t idx = (size_t)w * D + lane;
    out[idx] = val;
    acc[idx] = (acc[idx] + val) * scale;
}

extern "C" void kernel_launch(void* const* d_in, const int* in_sizes, int n_in,
                              void* d_out, int out_size, void* d_ws, size_t ws_size,
                              hipStream_t stream) {
    const int* ei      = (const int*)d_in[0];
    const float* uemb  = (const float*)d_in[1];
    const float* iemb  = (const float*)d_in[2];
    const float* Ws    = (const float*)d_in[3];
    const float* bs    = (const float*)d_in[4];

    const int E = in_sizes[0] / 2;
    const int U = in_sizes[1] / D;
    const int I = in_sizes[2] / D;
    const int N = U + I;
    const int L = in_sizes[3] / (D * D);
    const int ND = N * D;
    const int nbuk = (N + BUK_NODES - 1) >> BUK_SHIFT;

    float* buf     = (float*)d_ws;                       // [N, D] f32 (x ping)
    unsigned short* hs16 = (unsigned short*)(buf + ND);  // [N, D] bf16
    float* dinv    = (float*)(hs16 + ND);                // [N]
    int*   csr_src = (int*)(dinv + N);                   // [E]
    unsigned int* packed = (unsigned int*)(csr_src + E); // [E]
    int*   rowptr  = (int*)(packed + E);                 // [N+1]
    int*   bcount  = rowptr + N + 1;                     // [nbuk]
    int*   bbase   = bcount + MAX_NBUK;                  // [nbuk+1]
    int*   gfill   = bbase + MAX_NBUK + 1;               // [nbuk]

    float* acc = (float*)d_out;                          // [N, D]

    // ---- build CSR ----
    hipMemsetAsync(bcount, 0, nbuk * sizeof(int), stream);
    k_bucket_hist<<<512, 256, 0, stream>>>(ei, bcount, E, nbuk);
    k_scan_buckets<<<1, 512, 0, stream>>>(bcount, bbase, gfill, rowptr, nbuk, N, E);
    k_bucket_scatter<<<(E + TILE_E - 1) / TILE_E, 512, 0, stream>>>(ei, bbase, gfill,
                                                                   packed, E, nbuk);
    k_build_csr<<<nbuk, 256, 0, stream>>>(packed, bbase, rowptr, dinv, csr_src, N);

    // ---- acc = x0 ----
    k_init_acc<<<2048, 256, 0, stream>>>((const float4*)uemb, (const float4*)iemb,
                                         (float4*)acc, U * D / 4, ND / 4);

    // ---- layers ----
    const float* xin = nullptr;   // layer 0 reads emb directly
    for (int l = 0; l < L; ++l) {
        k_gemm_mfma<<<1024, 256, 0, stream>>>(xin, uemb, iemb, U,
                                              Ws + (size_t)l * D * D, dinv, hs16, N);
        k_aggregate<<<(N + 3) / 4, 256, 0, stream>>>(rowptr, csr_src, hs16, dinv,
                                                     bs + (size_t)l * D, buf, acc,
                                                     (l == L - 1) ? 1.0f / (L + 1) : 1.0f, N);
        xin = buf;
    }
}